// Round 3
// baseline (1326.428 us; speedup 1.0000x reference)
//
#include <hip/hip_runtime.h>

// Native clang vector type: accepted by __builtin_nontemporal_{load,store}.
typedef float vfloat4 __attribute__((ext_vector_type(4)));

// Grid-stride circular-buffer update: out[row] = (row-mi mod M) < B ? batch[rel] : mem[row].
// Flat over float4 elements; D4 = 256 float4/row (power of two -> shift/mask).
// Resident grid (2048 blocks x 256 thr = 32 waves/CU) streams ~100 float4/thread.
__global__ __launch_bounds__(256) void copy_update_rows(
        const vfloat4* __restrict__ mem,
        const vfloat4* __restrict__ batch,
        vfloat4* __restrict__ out,
        const int* __restrict__ d_mi,
        int M, int B, int MD4) {
    const int mi = *d_mi;
    const int stride = gridDim.x * blockDim.x;
    for (int g = blockIdx.x * blockDim.x + threadIdx.x; g < MD4; g += stride) {
        int row = g >> 8;            // D4 = 256
        int rel = row - mi;
        if (rel < 0) rel += M;
        vfloat4 v;
        if (rel < B) {
            v = batch[(rel << 8) | (g & 255)];
        } else {
            v = __builtin_nontemporal_load(&mem[g]);
        }
        __builtin_nontemporal_store(v, &out[g]);
    }
}

__global__ void copy_update_conf(const float* __restrict__ mem,
                                 const float* __restrict__ batch,
                                 float* __restrict__ out,
                                 const int* __restrict__ d_mi,
                                 int M, int B) {
    int i = blockIdx.x * blockDim.x + threadIdx.x;
    if (i >= M) return;
    int rel = i - *d_mi;
    if (rel < 0) rel += M;
    out[i] = (rel < B) ? batch[rel] : mem[i];
}

// Single block: mean of B confidences + utilization scalar.
__global__ void mean_and_util(const float* __restrict__ conf,
                              const int* __restrict__ d_mi,
                              const int* __restrict__ d_full,
                              float* __restrict__ out_mean,
                              float* __restrict__ out_util,
                              int B, int M) {
    __shared__ float warp_sums[8];
    float s = 0.0f;
    for (int i = threadIdx.x; i < B; i += blockDim.x) s += conf[i];
    #pragma unroll
    for (int off = 32; off > 0; off >>= 1) s += __shfl_down(s, off);
    int lane = threadIdx.x & 63;
    int wave = threadIdx.x >> 6;
    if (lane == 0) warp_sums[wave] = s;
    __syncthreads();
    if (threadIdx.x == 0) {
        int nwaves = (blockDim.x + 63) >> 6;
        float total = 0.0f;
        for (int w = 0; w < nwaves; ++w) total += warp_sums[w];
        out_mean[0] = total / (float)B;

        int mi = *d_mi;
        int ni = (mi + B) % M;
        bool wrapped = (mi + B) >= M;
        bool full = (*d_full != 0) || wrapped;
        out_util[0] = full ? 1.0f : (float)ni / (float)M;
    }
}

extern "C" void kernel_launch(void* const* d_in, const int* in_sizes, int n_in,
                              void* d_out, int out_size, void* d_ws, size_t ws_size,
                              hipStream_t stream) {
    const float* features     = (const float*)d_in[0];
    const float* predictions  = (const float*)d_in[1];
    const float* confidences  = (const float*)d_in[2];
    const float* mem_feat     = (const float*)d_in[3];
    const float* mem_pred     = (const float*)d_in[4];
    const float* mem_conf     = (const float*)d_in[5];
    const int*   d_mi         = (const int*)d_in[6];
    const int*   d_full       = (const int*)d_in[7];

    const int B   = in_sizes[2];          // 4096
    const int MD  = in_sizes[3];          // 102,400,000
    const int M   = in_sizes[5];          // 100,000
    const int MD4 = MD / 4;               // 25,600,000 float4s

    float* out       = (float*)d_out;
    float* out_feat  = out;
    float* out_pred  = out + (size_t)MD;
    float* out_conf  = out + (size_t)2 * MD;
    float* out_mean  = out_conf + M;
    float* out_util  = out_mean + 1;

    const int blocks = 2048;   // 8 blocks/CU * 256 CUs, 32 waves/CU resident

    copy_update_rows<<<blocks, 256, 0, stream>>>((const vfloat4*)mem_feat,
                                                 (const vfloat4*)features,
                                                 (vfloat4*)out_feat, d_mi, M, B, MD4);
    copy_update_rows<<<blocks, 256, 0, stream>>>((const vfloat4*)mem_pred,
                                                 (const vfloat4*)predictions,
                                                 (vfloat4*)out_pred, d_mi, M, B, MD4);
    copy_update_conf<<<(M + 255) / 256, 256, 0, stream>>>(mem_conf, confidences,
                                                          out_conf, d_mi, M, B);
    mean_and_util<<<1, 256, 0, stream>>>(confidences, d_mi, d_full,
                                         out_mean, out_util, B, M);
}

// Round 4
// 1317.817 us; speedup vs baseline: 1.0065x; 1.0065x over previous
//
#include <hip/hip_runtime.h>

typedef float vfloat4 __attribute__((ext_vector_type(4)));

// Grid-stride circular-buffer update: out[row] = (row-mi mod M) < B ? batch[rel] : mem[row].
// Flat over float4 elements; D4 = 256 float4/row (power of two -> shift/mask).
// 2048 blocks x 256 thr (8 blocks/CU), plain cached loads/stores (NT regressed in R3).
__global__ __launch_bounds__(256) void copy_update_rows(
        const vfloat4* __restrict__ mem,
        const vfloat4* __restrict__ batch,
        vfloat4* __restrict__ out,
        const int* __restrict__ d_mi,
        int M, int B, int MD4) {
    const int mi = *d_mi;
    const int stride = gridDim.x * blockDim.x;
    for (int g = blockIdx.x * blockDim.x + threadIdx.x; g < MD4; g += stride) {
        int row = g >> 8;            // D4 = 256
        int rel = row - mi;
        if (rel < 0) rel += M;
        out[g] = (rel < B) ? batch[(rel << 8) | (g & 255)] : mem[g];
    }
}

// Fused: conf circular update (all blocks) + mean/utilization scalars (block 0).
__global__ __launch_bounds__(256) void conf_mean_util(
        const float* __restrict__ mem,
        const float* __restrict__ batch,
        float* __restrict__ out_conf,
        float* __restrict__ out_mean,
        float* __restrict__ out_util,
        const int* __restrict__ d_mi,
        const int* __restrict__ d_full,
        int M, int B) {
    const int mi = *d_mi;
    int i = blockIdx.x * blockDim.x + threadIdx.x;
    if (i < M) {
        int rel = i - mi;
        if (rel < 0) rel += M;
        out_conf[i] = (rel < B) ? batch[rel] : mem[i];
    }
    if (blockIdx.x == 0) {
        __shared__ float warp_sums[4];
        float s = 0.0f;
        for (int k = threadIdx.x; k < B; k += blockDim.x) s += batch[k];
        #pragma unroll
        for (int off = 32; off > 0; off >>= 1) s += __shfl_down(s, off);
        int lane = threadIdx.x & 63;
        int wave = threadIdx.x >> 6;
        if (lane == 0) warp_sums[wave] = s;
        __syncthreads();
        if (threadIdx.x == 0) {
            float total = warp_sums[0] + warp_sums[1] + warp_sums[2] + warp_sums[3];
            out_mean[0] = total / (float)B;
            int ni = (mi + B) % M;
            bool wrapped = (mi + B) >= M;
            bool full = (*d_full != 0) || wrapped;
            out_util[0] = full ? 1.0f : (float)ni / (float)M;
        }
    }
}

extern "C" void kernel_launch(void* const* d_in, const int* in_sizes, int n_in,
                              void* d_out, int out_size, void* d_ws, size_t ws_size,
                              hipStream_t stream) {
    const float* features     = (const float*)d_in[0];
    const float* predictions  = (const float*)d_in[1];
    const float* confidences  = (const float*)d_in[2];
    const float* mem_feat     = (const float*)d_in[3];
    const float* mem_pred     = (const float*)d_in[4];
    const float* mem_conf     = (const float*)d_in[5];
    const int*   d_mi         = (const int*)d_in[6];
    const int*   d_full       = (const int*)d_in[7];

    const int B   = in_sizes[2];          // 4096
    const int MD  = in_sizes[3];          // 102,400,000
    const int M   = in_sizes[5];          // 100,000
    const int MD4 = MD / 4;               // 25,600,000 float4s

    float* out       = (float*)d_out;
    float* out_feat  = out;
    float* out_pred  = out + (size_t)MD;
    float* out_conf  = out + (size_t)2 * MD;
    float* out_mean  = out_conf + M;
    float* out_util  = out_mean + 1;

    const int blocks = 2048;   // 8 blocks/CU * 256 CUs

    copy_update_rows<<<blocks, 256, 0, stream>>>((const vfloat4*)mem_feat,
                                                 (const vfloat4*)features,
                                                 (vfloat4*)out_feat, d_mi, M, B, MD4);
    copy_update_rows<<<blocks, 256, 0, stream>>>((const vfloat4*)mem_pred,
                                                 (const vfloat4*)predictions,
                                                 (vfloat4*)out_pred, d_mi, M, B, MD4);
    conf_mean_util<<<(M + 255) / 256, 256, 0, stream>>>(mem_conf, confidences,
                                                        out_conf, out_mean, out_util,
                                                        d_mi, d_full, M, B);
}